// Round 5
// baseline (534.196 us; speedup 1.0000x reference)
//
#include <hip/hip_runtime.h>
#include <stdint.h>

// ---------------------------------------------------------------------------
// MD5Surrogate: 64-round scan of 3-layer MLP (22->256->256->16), B=16384.
// fp32 in/out. R15 = R14 with 4 independent barrier domains per CU:
//  NG=1 (16 rows/block), grid 1024, 512 thr, launch_bounds(512,8)
//  -> 4 blocks/CU x 8 waves = 32 waves/CU in 4 INDEPENDENT barrier groups.
//  R11 showed waves added inside one barrier group don't help (they share
//  the same phase drains); independent blocks interleave across each
//  other's barrier C/D stalls. Cost: per-CU L2 weight traffic doubles
//  (each block reads the full 128KB W2 round slice) -> ~4.2TB/s/XCD,
//  just under the L2 ceiling; LDS 23.4KB/block (4x fits in 160KB).
// From R14: distributed L3 (wave0 only, a3/bb3 live range contained inside
// the branch -- no cross-barrier conditional liveness, no spill), word
// scatter on wave1, barrier D publishes x. bf16 hi/lo x, A&S 7.1.25 gelu,
// bias-in-accumulator, a2 loaded per-tt in-loop (compiler-scheduled).
// ---------------------------------------------------------------------------

using bf16x8   = __attribute__((ext_vector_type(8))) __bf16;
using floatx4  = __attribute__((ext_vector_type(4))) float;
using floatx2  = __attribute__((ext_vector_type(2))) float;
using ushort4v = __attribute__((ext_vector_type(4))) unsigned short;

__constant__ int c_sched[64] = {
  0,1,2,3,4,5,6,7,8,9,10,11,12,13,14,15,
  1,6,11,0,5,10,15,4,9,14,3,8,13,2,7,12,
  5,8,11,14,1,4,7,10,13,0,3,6,9,12,15,2,
  0,7,14,5,12,3,10,1,8,15,6,13,4,11,2,9
};
__constant__ float c_shift[64] = {
  7,12,17,22,7,12,17,22,7,12,17,22,7,12,17,22,
  5,9,14,20,5,9,14,20,5,9,14,20,5,9,14,20,
  4,11,16,23,4,11,16,23,4,11,16,23,4,11,16,23,
  6,10,15,21,6,10,15,21,6,10,15,21,6,10,15,21
};

__device__ __forceinline__ unsigned short bfbits(__bf16 b) {
  union { __bf16 b; unsigned short u; } v; v.b = b; return v.u;
}
// gelu via A&S 7.1.25 (|eps|<=2.5e-5), constants folded, exp2-scaled
__device__ __forceinline__ float gelu_f(float x) {
  float ax = fabsf(x);
  float t  = __builtin_amdgcn_rcpf(__builtin_fmaf(0.33270222f, ax, 1.0f));
  float e  = __builtin_amdgcn_exp2f(x * x * -0.72134752f);
  float poly = t * __builtin_fmaf(t, __builtin_fmaf(t, 0.7478556f, -0.0958798f),
                                  0.3480242f);
  float er = __builtin_fmaf(-poly, e, 1.0f);
  er = copysignf(er, x);
  float hx = 0.5f * x;
  return __builtin_fmaf(hx, er, hx);
}
__device__ __forceinline__ floatx4 mfma16(bf16x8 a, bf16x8 b, floatx4 c) {
  return __builtin_amdgcn_mfma_f32_16x16x32_bf16(a, b, c, 0, 0, 0);
}
struct BfPair { unsigned short h, l; };
__device__ __forceinline__ BfPair split2(float s) {
  __bf16 hb = (__bf16)s;
  __bf16 lb = (__bf16)(s - (float)hb);
  BfPair p; p.h = bfbits(hb); p.l = bfbits(lb); return p;
}

// ---------------------------------------------------------------------------
// Packed-weight layout: fragment = 64 lanes x 8 bf16. A[m][k]: m=lane&15,
// k=8*(lane>>4)+j.  P1 (r*16+t): W1[r][k][16t+m] (k>=22 -> 0)
//                   P2 ((r*16+t)*8+c): W2[r][32c+k'][16t+m]
//                   P3 (r*8+c): W3[r][32c+k'][m]
// ---------------------------------------------------------------------------
#define N1G (64*16*64)
#define N2G (64*16*8*64)
#define N3G (64*8*64)

__global__ void pack_w(const float* __restrict__ W1,
                       const float* __restrict__ W2,
                       const float* __restrict__ W3,
                       unsigned short* __restrict__ P) {
  int gid = blockIdx.x * blockDim.x + threadIdx.x;
  if (gid >= N1G + N2G + N3G) return;
  unsigned short v[8];
  unsigned short* dst;
  if (gid < N1G) {
    int lane = gid & 63, t = (gid >> 6) & 15, r = gid >> 10;
    int qq = lane >> 4, mm = lane & 15;
    #pragma unroll
    for (int j = 0; j < 8; ++j) {
      int k = 8*qq + j;
      v[j] = (k < 22) ? bfbits((__bf16)W1[(r*22 + k)*256 + 16*t + mm]) : (unsigned short)0;
    }
    dst = P + (size_t)gid * 8;
  } else if (gid < N1G + N2G) {
    int g = gid - N1G;
    int lane = g & 63, c = (g >> 6) & 7, t = (g >> 9) & 15, r = g >> 13;
    int qq = lane >> 4, mm = lane & 15;
    #pragma unroll
    for (int j = 0; j < 8; ++j) {
      int k = 32*c + 8*qq + j;
      v[j] = bfbits((__bf16)W2[((size_t)r*256 + k)*256 + 16*t + mm]);
    }
    dst = P + (size_t)(N1G + g) * 8;
  } else {
    int g = gid - N1G - N2G;
    int lane = g & 63, c = (g >> 6) & 7, r = g >> 9;
    int qq = lane >> 4, mm = lane & 15;
    #pragma unroll
    for (int j = 0; j < 8; ++j) {
      int k = 32*c + 8*qq + j;
      v[j] = bfbits((__bf16)W3[(r*256 + k)*16 + mm]);
    }
    dst = P + (size_t)(N1G + N2G + g) * 8;
  }
  ushort4v lo = { v[0],v[1],v[2],v[3] }, hi = { v[4],v[5],v[6],v[7] };
  *(ushort4v*)dst = lo;
  *(ushort4v*)(dst + 4) = hi;
}

// ---------------------------------------------------------------------------
#define NG  1    // row-groups per block (16 rows/block)
#define TT  2    // feature sub-tiles per wave (8 waves x 32 features = 256)
#define SXW 36   // x row stride (ushorts)
#define SH 264   // h row stride
#define SM 66    // msg row stride

__global__ __launch_bounds__(512, 8) void md5_main(
    const float* __restrict__ msg,   // (16384,64)
    const float* __restrict__ st0,   // (16384,16)
    const float* __restrict__ b1,    // (64,256)
    const float* __restrict__ b2,    // (64,256)
    const float* __restrict__ b3,    // (64,16)
    const unsigned short* __restrict__ P,
    float* __restrict__ out)         // (16384,16)
{
  __shared__ unsigned short xh[16][SXW], xl[16][SXW];
  __shared__ unsigned short hA[16][SH], hB[16][SH];
  __shared__ unsigned short msgb[16][SM], msgl[16][SM];

  const int tid  = threadIdx.x;
  const int wv   = tid >> 6;        // 0..7
  const int lane = tid & 63;
  const int q    = lane >> 4;
  const int ln   = lane & 15;
  const int row0 = blockIdx.x * 16;

  const unsigned short* P1 = P;
  const unsigned short* P2 = P + (size_t)N1G * 8;
  const unsigned short* P3 = P + (size_t)(N1G + N2G) * 8;

  // zero x buffers once (pad cols 22..35 must stay 0 forever)
  for (int i = tid; i < 16*SXW; i += 512) {
    (&xh[0][0])[i] = 0; (&xl[0][0])[i] = 0;
  }
  // msg preload (shared, hi/lo): 16 rows x 64 = 1024 elems / 512 thr = 2 each
  {
    int idx = tid * 2, rr = idx >> 6, cc = idx & 63;
    floatx2 v0 = *(const floatx2*)(msg + (size_t)(row0 + rr)*64 + cc);
    #pragma unroll
    for (int j = 0; j < 2; ++j) {
      BfPair p0 = split2(v0[j]);
      msgb[rr][cc + j] = p0.h;  msgl[rr][cc + j] = p0.l;
    }
  }
  // init state: one wave suffices (ordered by the barrier below)
  if (wv == 0) {
    floatx4 v = *(const floatx4*)(st0 + (size_t)(row0 + ln)*16 + 4*q);
    ushort4v h4, l4;
    #pragma unroll
    for (int e = 0; e < 4; ++e) { BfPair p = split2(v[e]); h4[e] = p.h; l4[e] = p.l; }
    *(ushort4v*)&xh[ln][4*q] = h4;
    *(ushort4v*)&xl[ln][4*q] = l4;
  }
  __syncthreads();   // msgb/msgl + state + zero-pads ready
  // round-0 word+rinfo: every wave writes the full (identical) set so its own
  // L1 reads are covered without another barrier (benign identical-value race)
  if (lane < 16) {
    int n = lane;
    int s = c_sched[0];
    BfPair i1p = split2(c_shift[0] / 25.0f);
    #pragma unroll
    for (int j = 0; j < 4; ++j) {
      xh[n][16+j] = msgb[n][4*s+j];
      xl[n][16+j] = msgl[n][4*s+j];
    }
    xh[n][20] = 0;     xl[n][20] = 0;   // round 0: i/64 = 0
    xh[n][21] = i1p.h; xl[n][21] = i1p.l;
  }

  #pragma unroll 1
  for (int r = 0; r < 64; ++r) {
    // -------- Layer 1: x @ W1 -> h1 (own 32-feature slice) ----
    floatx4 bb1[TT];
    bf16x8  a1[TT];
    const unsigned short* p1 = P1 + ((size_t)(r*16 + TT*wv)*64 + lane)*8;
    #pragma unroll
    for (int tt = 0; tt < TT; ++tt) {
      a1[tt]  = *(const bf16x8*)(p1 + (size_t)tt*512);
      bb1[tt] = *(const floatx4*)(b1 + r*256 + (TT*wv + tt)*16 + 4*q);
    }
    bf16x8 bxh = *(const bf16x8*)&xh[ln][8*q];
    bf16x8 bxl = *(const bf16x8*)&xl[ln][8*q];
    #pragma unroll
    for (int tt = 0; tt < TT; ++tt) {
      int f0 = (TT*wv + tt)*16 + 4*q;
      floatx4 acc = bb1[tt];
      acc = mfma16(a1[tt], bxl, acc);
      acc = mfma16(a1[tt], bxh, acc);
      ushort4v h4;
      #pragma unroll
      for (int e = 0; e < 4; ++e) h4[e] = bfbits((__bf16)gelu_f(acc[e]));
      *(ushort4v*)&hA[ln][f0] = h4;
    }
    __syncthreads();                       // (B) h1 ready; hB free

    // -------- Layer 2: h1 @ W2 -> h2 (own slice) --------
    floatx4 bb2[TT];
    #pragma unroll
    for (int tt = 0; tt < TT; ++tt)
      bb2[tt] = *(const floatx4*)(b2 + r*256 + (TT*wv + tt)*16 + 4*q);

    bf16x8 Bf[8];
    #pragma unroll
    for (int c = 0; c < 8; ++c) Bf[c] = *(const bf16x8*)&hA[ln][32*c + 8*q];

    const unsigned short* p2 = P2 + ((size_t)((r*16 + TT*wv)*8)*64 + lane)*8;
    #pragma unroll
    for (int tt = 0; tt < TT; ++tt) {
      bf16x8 a2[8];
      #pragma unroll
      for (int c = 0; c < 8; ++c)
        a2[c] = *(const bf16x8*)(p2 + (size_t)(tt*8 + c)*512);
      int f0 = (TT*wv + tt)*16 + 4*q;
      floatx4 acc = bb2[tt];
      #pragma unroll
      for (int c = 0; c < 8; ++c) acc = mfma16(a2[c], Bf[c], acc);
      ushort4v h4;
      #pragma unroll
      for (int e = 0; e < 4; ++e) h4[e] = bfbits((__bf16)gelu_f(acc[e]));
      *(ushort4v*)&hB[ln][f0] = h4;
    }
    __syncthreads();                       // (C) h2 ready

    // -------- Layer 3 (wave 0 only; live range contained -> no spill) -----
    if (wv == 0) {
      const unsigned short* p3 = P3 + ((size_t)(r*8)*64 + lane)*8;
      bf16x8 a3[8];
      #pragma unroll
      for (int c = 0; c < 8; ++c) a3[c] = *(const bf16x8*)(p3 + (size_t)c*512);
      floatx4 s = *(const floatx4*)(b3 + r*16 + 4*q);
      #pragma unroll
      for (int c = 0; c < 8; ++c) {
        bf16x8 bh = *(const bf16x8*)&hB[ln][32*c + 8*q];
        s = mfma16(a3[c], bh, s);
      }
      if (r == 63) {
        *(floatx4*)(out + (size_t)(row0 + ln)*16 + 4*q) = s;
      } else {
        ushort4v h4, l4;
        #pragma unroll
        for (int e = 0; e < 4; ++e) { BfPair p = split2(s[e]); h4[e] = p.h; l4[e] = p.l; }
        *(ushort4v*)&xh[ln][4*q] = h4;
        *(ushort4v*)&xl[ln][4*q] = l4;
      }
    }
    // word + rinfo for next round: wave 1 only (published by barrier D)
    if (wv == 1 && lane < 16 && r < 63) {
      int n = lane;
      int sc = c_sched[r+1];
      float i0 = (float)(r+1) * 0.015625f;   // exact in bf16
      BfPair i1p = split2(c_shift[r+1] / 25.0f);
      #pragma unroll
      for (int j = 0; j < 4; ++j) {
        xh[n][16+j] = msgb[n][4*sc+j];
        xl[n][16+j] = msgl[n][4*sc+j];
      }
      xh[n][20] = bfbits((__bf16)i0); xl[n][20] = 0;
      xh[n][21] = i1p.h;              xl[n][21] = i1p.l;
    }
    if (r < 63) __syncthreads();           // (D) x ready for next L1
  }
}

// ---------------------------------------------------------------------------
extern "C" void kernel_launch(void* const* d_in, const int* in_sizes, int n_in,
                              void* d_out, int out_size, void* d_ws, size_t ws_size,
                              hipStream_t stream) {
  const float* msg = (const float*)d_in[0];
  const float* st0 = (const float*)d_in[1];
  const float* W1  = (const float*)d_in[2];
  const float* b1  = (const float*)d_in[3];
  const float* W2  = (const float*)d_in[4];
  const float* b2  = (const float*)d_in[5];
  const float* W3  = (const float*)d_in[6];
  const float* b3  = (const float*)d_in[7];
  float* out = (float*)d_out;
  (void)in_sizes; (void)n_in; (void)out_size; (void)ws_size;

  unsigned short* P = (unsigned short*)d_ws;
  const int totalGroups = N1G + N2G + N3G;   // 622592
  pack_w<<<(totalGroups + 255) / 256, 256, 0, stream>>>(W1, W2, W3, P);
  md5_main<<<1024, 512, 0, stream>>>(msg, st0, b1, b2, b3, P, out);
}

// Round 6
// 524.197 us; speedup vs baseline: 1.0191x; 1.0191x over previous
//
#include <hip/hip_runtime.h>
#include <stdint.h>

// ---------------------------------------------------------------------------
// MD5Surrogate: 64-round scan of 3-layer MLP (22->256->256->16), B=16384.
// fp32 in/out. R16: 256-thread blocks (4 waves), grid 1024,
// launch_bounds(256,4) -> 4 blocks/CU x 4 waves = 16 waves/CU (same as R14)
// but in 4 INDEPENDENT barrier domains, with VGPR cap 128 (vs R14's 60).
//  - R15 proved launch_bounds(512,8)'s VGPR=32 strangles ILP (511us).
//  - R11 proved extra waves in the SAME barrier domain don't help.
//  - R16 isolates domain count with per-wave ILP held >= R14: staggered
//    blocks fill each other's barrier-C/D drains.
// Per-wave round work identical to R14 (TT=4: 64 features/wave). Per-CU L2
// weight traffic ~600KB/round ~ 2TB/s/XCD -- under the ceiling.
// From R14: distributed L3 (wave0, a3/bb3 live range contained inside the
// branch -> no spill), word scatter wave1, barrier D publishes x, bf16 hi/lo
// x, A&S 7.1.25 gelu, bias-in-accumulator, a2 loaded per-tt in-loop.
// ---------------------------------------------------------------------------

using bf16x8   = __attribute__((ext_vector_type(8))) __bf16;
using floatx4  = __attribute__((ext_vector_type(4))) float;
using ushort4v = __attribute__((ext_vector_type(4))) unsigned short;

__constant__ int c_sched[64] = {
  0,1,2,3,4,5,6,7,8,9,10,11,12,13,14,15,
  1,6,11,0,5,10,15,4,9,14,3,8,13,2,7,12,
  5,8,11,14,1,4,7,10,13,0,3,6,9,12,15,2,
  0,7,14,5,12,3,10,1,8,15,6,13,4,11,2,9
};
__constant__ float c_shift[64] = {
  7,12,17,22,7,12,17,22,7,12,17,22,7,12,17,22,
  5,9,14,20,5,9,14,20,5,9,14,20,5,9,14,20,
  4,11,16,23,4,11,16,23,4,11,16,23,4,11,16,23,
  6,10,15,21,6,10,15,21,6,10,15,21,6,10,15,21
};

__device__ __forceinline__ unsigned short bfbits(__bf16 b) {
  union { __bf16 b; unsigned short u; } v; v.b = b; return v.u;
}
// gelu via A&S 7.1.25 (|eps|<=2.5e-5), constants folded, exp2-scaled
__device__ __forceinline__ float gelu_f(float x) {
  float ax = fabsf(x);
  float t  = __builtin_amdgcn_rcpf(__builtin_fmaf(0.33270222f, ax, 1.0f));
  float e  = __builtin_amdgcn_exp2f(x * x * -0.72134752f);
  float poly = t * __builtin_fmaf(t, __builtin_fmaf(t, 0.7478556f, -0.0958798f),
                                  0.3480242f);
  float er = __builtin_fmaf(-poly, e, 1.0f);
  er = copysignf(er, x);
  float hx = 0.5f * x;
  return __builtin_fmaf(hx, er, hx);
}
__device__ __forceinline__ floatx4 mfma16(bf16x8 a, bf16x8 b, floatx4 c) {
  return __builtin_amdgcn_mfma_f32_16x16x32_bf16(a, b, c, 0, 0, 0);
}
struct BfPair { unsigned short h, l; };
__device__ __forceinline__ BfPair split2(float s) {
  __bf16 hb = (__bf16)s;
  __bf16 lb = (__bf16)(s - (float)hb);
  BfPair p; p.h = bfbits(hb); p.l = bfbits(lb); return p;
}

// ---------------------------------------------------------------------------
// Packed-weight layout: fragment = 64 lanes x 8 bf16. A[m][k]: m=lane&15,
// k=8*(lane>>4)+j.  P1 (r*16+t): W1[r][k][16t+m] (k>=22 -> 0)
//                   P2 ((r*16+t)*8+c): W2[r][32c+k'][16t+m]
//                   P3 (r*8+c): W3[r][32c+k'][m]
// ---------------------------------------------------------------------------
#define N1G (64*16*64)
#define N2G (64*16*8*64)
#define N3G (64*8*64)

__global__ void pack_w(const float* __restrict__ W1,
                       const float* __restrict__ W2,
                       const float* __restrict__ W3,
                       unsigned short* __restrict__ P) {
  int gid = blockIdx.x * blockDim.x + threadIdx.x;
  if (gid >= N1G + N2G + N3G) return;
  unsigned short v[8];
  unsigned short* dst;
  if (gid < N1G) {
    int lane = gid & 63, t = (gid >> 6) & 15, r = gid >> 10;
    int qq = lane >> 4, mm = lane & 15;
    #pragma unroll
    for (int j = 0; j < 8; ++j) {
      int k = 8*qq + j;
      v[j] = (k < 22) ? bfbits((__bf16)W1[(r*22 + k)*256 + 16*t + mm]) : (unsigned short)0;
    }
    dst = P + (size_t)gid * 8;
  } else if (gid < N1G + N2G) {
    int g = gid - N1G;
    int lane = g & 63, c = (g >> 6) & 7, t = (g >> 9) & 15, r = g >> 13;
    int qq = lane >> 4, mm = lane & 15;
    #pragma unroll
    for (int j = 0; j < 8; ++j) {
      int k = 32*c + 8*qq + j;
      v[j] = bfbits((__bf16)W2[((size_t)r*256 + k)*256 + 16*t + mm]);
    }
    dst = P + (size_t)(N1G + g) * 8;
  } else {
    int g = gid - N1G - N2G;
    int lane = g & 63, c = (g >> 6) & 7, r = g >> 9;
    int qq = lane >> 4, mm = lane & 15;
    #pragma unroll
    for (int j = 0; j < 8; ++j) {
      int k = 32*c + 8*qq + j;
      v[j] = bfbits((__bf16)W3[(r*256 + k)*16 + mm]);
    }
    dst = P + (size_t)(N1G + N2G + g) * 8;
  }
  ushort4v lo = { v[0],v[1],v[2],v[3] }, hi = { v[4],v[5],v[6],v[7] };
  *(ushort4v*)dst = lo;
  *(ushort4v*)(dst + 4) = hi;
}

// ---------------------------------------------------------------------------
#define TT  4    // feature sub-tiles per wave (4 waves x 64 features = 256)
#define SXW 36   // x row stride (ushorts)
#define SH 264   // h row stride
#define SM 66    // msg row stride

__global__ __launch_bounds__(256, 4) void md5_main(
    const float* __restrict__ msg,   // (16384,64)
    const float* __restrict__ st0,   // (16384,16)
    const float* __restrict__ b1,    // (64,256)
    const float* __restrict__ b2,    // (64,256)
    const float* __restrict__ b3,    // (64,16)
    const unsigned short* __restrict__ P,
    float* __restrict__ out)         // (16384,16)
{
  __shared__ unsigned short xh[16][SXW], xl[16][SXW];
  __shared__ unsigned short hA[16][SH], hB[16][SH];
  __shared__ unsigned short msgb[16][SM], msgl[16][SM];

  const int tid  = threadIdx.x;
  const int wv   = tid >> 6;        // 0..3
  const int lane = tid & 63;
  const int q    = lane >> 4;
  const int ln   = lane & 15;
  const int row0 = blockIdx.x * 16;

  const unsigned short* P1 = P;
  const unsigned short* P2 = P + (size_t)N1G * 8;
  const unsigned short* P3 = P + (size_t)(N1G + N2G) * 8;

  // zero x buffers once (pad cols 22..35 must stay 0 forever)
  for (int i = tid; i < 16*SXW; i += 256) {
    (&xh[0][0])[i] = 0; (&xl[0][0])[i] = 0;
  }
  // msg preload (shared, hi/lo): 16 rows x 64 = 1024 elems / 256 thr = 4 each
  {
    int idx = tid * 4, rr = idx >> 6, cc = idx & 63;
    floatx4 v0 = *(const floatx4*)(msg + (size_t)(row0 + rr)*64 + cc);
    #pragma unroll
    for (int j = 0; j < 4; ++j) {
      BfPair p0 = split2(v0[j]);
      msgb[rr][cc + j] = p0.h;  msgl[rr][cc + j] = p0.l;
    }
  }
  // init state: one wave suffices (ordered by the barrier below)
  if (wv == 0) {
    floatx4 v = *(const floatx4*)(st0 + (size_t)(row0 + ln)*16 + 4*q);
    ushort4v h4, l4;
    #pragma unroll
    for (int e = 0; e < 4; ++e) { BfPair p = split2(v[e]); h4[e] = p.h; l4[e] = p.l; }
    *(ushort4v*)&xh[ln][4*q] = h4;
    *(ushort4v*)&xl[ln][4*q] = l4;
  }
  __syncthreads();   // msgb/msgl + state + zero-pads ready
  // round-0 word+rinfo: every wave writes the full (identical) set so its own
  // L1 reads are covered without another barrier (benign identical-value race)
  if (lane < 16) {
    int n = lane;
    int s = c_sched[0];
    BfPair i1p = split2(c_shift[0] / 25.0f);
    #pragma unroll
    for (int j = 0; j < 4; ++j) {
      xh[n][16+j] = msgb[n][4*s+j];
      xl[n][16+j] = msgl[n][4*s+j];
    }
    xh[n][20] = 0;     xl[n][20] = 0;   // round 0: i/64 = 0
    xh[n][21] = i1p.h; xl[n][21] = i1p.l;
  }

  #pragma unroll 1
  for (int r = 0; r < 64; ++r) {
    // -------- Layer 1: x @ W1 -> h1 (own 64-feature slice) ----
    floatx4 bb1[TT];
    bf16x8  a1[TT];
    const unsigned short* p1 = P1 + ((size_t)(r*16 + TT*wv)*64 + lane)*8;
    #pragma unroll
    for (int tt = 0; tt < TT; ++tt) {
      a1[tt]  = *(const bf16x8*)(p1 + (size_t)tt*512);
      bb1[tt] = *(const floatx4*)(b1 + r*256 + (TT*wv + tt)*16 + 4*q);
    }
    bf16x8 bxh = *(const bf16x8*)&xh[ln][8*q];
    bf16x8 bxl = *(const bf16x8*)&xl[ln][8*q];
    #pragma unroll
    for (int tt = 0; tt < TT; ++tt) {
      int f0 = (TT*wv + tt)*16 + 4*q;
      floatx4 acc = bb1[tt];
      acc = mfma16(a1[tt], bxl, acc);
      acc = mfma16(a1[tt], bxh, acc);
      ushort4v h4;
      #pragma unroll
      for (int e = 0; e < 4; ++e) h4[e] = bfbits((__bf16)gelu_f(acc[e]));
      *(ushort4v*)&hA[ln][f0] = h4;
    }
    __syncthreads();                       // (B) h1 ready; hB free

    // -------- Layer 2: h1 @ W2 -> h2 (own slice) --------
    floatx4 bb2[TT];
    #pragma unroll
    for (int tt = 0; tt < TT; ++tt)
      bb2[tt] = *(const floatx4*)(b2 + r*256 + (TT*wv + tt)*16 + 4*q);

    bf16x8 Bf[8];
    #pragma unroll
    for (int c = 0; c < 8; ++c) Bf[c] = *(const bf16x8*)&hA[ln][32*c + 8*q];

    const unsigned short* p2 = P2 + ((size_t)((r*16 + TT*wv)*8)*64 + lane)*8;
    #pragma unroll
    for (int tt = 0; tt < TT; ++tt) {
      bf16x8 a2[8];
      #pragma unroll
      for (int c = 0; c < 8; ++c)
        a2[c] = *(const bf16x8*)(p2 + (size_t)(tt*8 + c)*512);
      int f0 = (TT*wv + tt)*16 + 4*q;
      floatx4 acc = bb2[tt];
      #pragma unroll
      for (int c = 0; c < 8; ++c) acc = mfma16(a2[c], Bf[c], acc);
      ushort4v h4;
      #pragma unroll
      for (int e = 0; e < 4; ++e) h4[e] = bfbits((__bf16)gelu_f(acc[e]));
      *(ushort4v*)&hB[ln][f0] = h4;
    }
    __syncthreads();                       // (C) h2 ready

    // -------- Layer 3 (wave 0 only; live range contained -> no spill) -----
    if (wv == 0) {
      const unsigned short* p3 = P3 + ((size_t)(r*8)*64 + lane)*8;
      bf16x8 a3[8];
      #pragma unroll
      for (int c = 0; c < 8; ++c) a3[c] = *(const bf16x8*)(p3 + (size_t)c*512);
      floatx4 s = *(const floatx4*)(b3 + r*16 + 4*q);
      #pragma unroll
      for (int c = 0; c < 8; ++c) {
        bf16x8 bh = *(const bf16x8*)&hB[ln][32*c + 8*q];
        s = mfma16(a3[c], bh, s);
      }
      if (r == 63) {
        *(floatx4*)(out + (size_t)(row0 + ln)*16 + 4*q) = s;
      } else {
        ushort4v h4, l4;
        #pragma unroll
        for (int e = 0; e < 4; ++e) { BfPair p = split2(s[e]); h4[e] = p.h; l4[e] = p.l; }
        *(ushort4v*)&xh[ln][4*q] = h4;
        *(ushort4v*)&xl[ln][4*q] = l4;
      }
    }
    // word + rinfo for next round: wave 1 only (published by barrier D)
    if (wv == 1 && lane < 16 && r < 63) {
      int n = lane;
      int sc = c_sched[r+1];
      float i0 = (float)(r+1) * 0.015625f;   // exact in bf16
      BfPair i1p = split2(c_shift[r+1] / 25.0f);
      #pragma unroll
      for (int j = 0; j < 4; ++j) {
        xh[n][16+j] = msgb[n][4*sc+j];
        xl[n][16+j] = msgl[n][4*sc+j];
      }
      xh[n][20] = bfbits((__bf16)i0); xl[n][20] = 0;
      xh[n][21] = i1p.h;              xl[n][21] = i1p.l;
    }
    if (r < 63) __syncthreads();           // (D) x ready for next L1
  }
}

// ---------------------------------------------------------------------------
extern "C" void kernel_launch(void* const* d_in, const int* in_sizes, int n_in,
                              void* d_out, int out_size, void* d_ws, size_t ws_size,
                              hipStream_t stream) {
  const float* msg = (const float*)d_in[0];
  const float* st0 = (const float*)d_in[1];
  const float* W1  = (const float*)d_in[2];
  const float* b1  = (const float*)d_in[3];
  const float* W2  = (const float*)d_in[4];
  const float* b2  = (const float*)d_in[5];
  const float* W3  = (const float*)d_in[6];
  const float* b3  = (const float*)d_in[7];
  float* out = (float*)d_out;
  (void)in_sizes; (void)n_in; (void)out_size; (void)ws_size;

  unsigned short* P = (unsigned short*)d_ws;
  const int totalGroups = N1G + N2G + N3G;   // 622592
  pack_w<<<(totalGroups + 255) / 256, 256, 0, stream>>>(W1, W2, W3, P);
  md5_main<<<1024, 256, 0, stream>>>(msg, st0, b1, b2, b3, P, out);
}

// Round 7
// 418.812 us; speedup vs baseline: 1.2755x; 1.2516x over previous
//
#include <hip/hip_runtime.h>
#include <stdint.h>

// ---------------------------------------------------------------------------
// MD5Surrogate: 64-round scan of 3-layer MLP (22->256->256->16), B=16384.
// fp32 in/out. R17 = R14 (best: 400us kernel) + two non-compiler-coverable
// latency fixes:
//  (1) Cross-barrier prefetch of next round's a1/bb1/bb2 (20 VGPRs, uniform,
//      issued right after barrier C; consumed after barrier D). hipcc never
//      hoists loads across s_barrier, so the ~300cy L2 latency of these was
//      fully exposed at round start / L2 start. Unconditional + small ->
//      no R12/R13-style spill (check: WRITE_SIZE stays ~1MB).
//  (2) L3 SIMD-parity balance: even blocks run L3 on waves {0,1} (SIMDs 0,1),
//      odd blocks on waves {2,3} (SIMDs 2,3); scatter wave = l3w^2. Without
//      this, both co-resident blocks concentrate L3 on SIMDs 0/1 while 2/3
//      idle through every L3 phase.
// Occupancy ladder closed: R11 (8w same domain), R15 (VGPR32), R16 (NG=1,
// 4 domains) all lost to R14's 2 domains x 8 waves x NG=2.
// From R14: distributed L3 (a3/bb3 live range contained inside branch -> no
// spill), word scatter on its own wave, barrier D publishes x, bf16 hi/lo x,
// A&S 7.1.25 gelu, bias-in-accumulator, a2 per-tt in-loop (compiler already
// pipelines straight-line unrolled loads; R15/R16 proved reg-capping it is
// what kills perf, not the schedule).
// ---------------------------------------------------------------------------

using bf16x8   = __attribute__((ext_vector_type(8))) __bf16;
using floatx4  = __attribute__((ext_vector_type(4))) float;
using ushort4v = __attribute__((ext_vector_type(4))) unsigned short;

__constant__ int c_sched[64] = {
  0,1,2,3,4,5,6,7,8,9,10,11,12,13,14,15,
  1,6,11,0,5,10,15,4,9,14,3,8,13,2,7,12,
  5,8,11,14,1,4,7,10,13,0,3,6,9,12,15,2,
  0,7,14,5,12,3,10,1,8,15,6,13,4,11,2,9
};
__constant__ float c_shift[64] = {
  7,12,17,22,7,12,17,22,7,12,17,22,7,12,17,22,
  5,9,14,20,5,9,14,20,5,9,14,20,5,9,14,20,
  4,11,16,23,4,11,16,23,4,11,16,23,4,11,16,23,
  6,10,15,21,6,10,15,21,6,10,15,21,6,10,15,21
};

__device__ __forceinline__ unsigned short bfbits(__bf16 b) {
  union { __bf16 b; unsigned short u; } v; v.b = b; return v.u;
}
// gelu via A&S 7.1.25 (|eps|<=2.5e-5), constants folded, exp2-scaled
__device__ __forceinline__ float gelu_f(float x) {
  float ax = fabsf(x);
  float t  = __builtin_amdgcn_rcpf(__builtin_fmaf(0.33270222f, ax, 1.0f));
  float e  = __builtin_amdgcn_exp2f(x * x * -0.72134752f);
  float poly = t * __builtin_fmaf(t, __builtin_fmaf(t, 0.7478556f, -0.0958798f),
                                  0.3480242f);
  float er = __builtin_fmaf(-poly, e, 1.0f);
  er = copysignf(er, x);
  float hx = 0.5f * x;
  return __builtin_fmaf(hx, er, hx);
}
__device__ __forceinline__ floatx4 mfma16(bf16x8 a, bf16x8 b, floatx4 c) {
  return __builtin_amdgcn_mfma_f32_16x16x32_bf16(a, b, c, 0, 0, 0);
}
struct BfPair { unsigned short h, l; };
__device__ __forceinline__ BfPair split2(float s) {
  __bf16 hb = (__bf16)s;
  __bf16 lb = (__bf16)(s - (float)hb);
  BfPair p; p.h = bfbits(hb); p.l = bfbits(lb); return p;
}

// ---------------------------------------------------------------------------
// Packed-weight layout: fragment = 64 lanes x 8 bf16. A[m][k]: m=lane&15,
// k=8*(lane>>4)+j.  P1 (r*16+t): W1[r][k][16t+m] (k>=22 -> 0)
//                   P2 ((r*16+t)*8+c): W2[r][32c+k'][16t+m]
//                   P3 (r*8+c): W3[r][32c+k'][m]
// ---------------------------------------------------------------------------
#define N1G (64*16*64)
#define N2G (64*16*8*64)
#define N3G (64*8*64)

__global__ void pack_w(const float* __restrict__ W1,
                       const float* __restrict__ W2,
                       const float* __restrict__ W3,
                       unsigned short* __restrict__ P) {
  int gid = blockIdx.x * blockDim.x + threadIdx.x;
  if (gid >= N1G + N2G + N3G) return;
  unsigned short v[8];
  unsigned short* dst;
  if (gid < N1G) {
    int lane = gid & 63, t = (gid >> 6) & 15, r = gid >> 10;
    int qq = lane >> 4, mm = lane & 15;
    #pragma unroll
    for (int j = 0; j < 8; ++j) {
      int k = 8*qq + j;
      v[j] = (k < 22) ? bfbits((__bf16)W1[(r*22 + k)*256 + 16*t + mm]) : (unsigned short)0;
    }
    dst = P + (size_t)gid * 8;
  } else if (gid < N1G + N2G) {
    int g = gid - N1G;
    int lane = g & 63, c = (g >> 6) & 7, t = (g >> 9) & 15, r = g >> 13;
    int qq = lane >> 4, mm = lane & 15;
    #pragma unroll
    for (int j = 0; j < 8; ++j) {
      int k = 32*c + 8*qq + j;
      v[j] = bfbits((__bf16)W2[((size_t)r*256 + k)*256 + 16*t + mm]);
    }
    dst = P + (size_t)(N1G + g) * 8;
  } else {
    int g = gid - N1G - N2G;
    int lane = g & 63, c = (g >> 6) & 7, r = g >> 9;
    int qq = lane >> 4, mm = lane & 15;
    #pragma unroll
    for (int j = 0; j < 8; ++j) {
      int k = 32*c + 8*qq + j;
      v[j] = bfbits((__bf16)W3[(r*256 + k)*16 + mm]);
    }
    dst = P + (size_t)(N1G + N2G + g) * 8;
  }
  ushort4v lo = { v[0],v[1],v[2],v[3] }, hi = { v[4],v[5],v[6],v[7] };
  *(ushort4v*)dst = lo;
  *(ushort4v*)(dst + 4) = hi;
}

// ---------------------------------------------------------------------------
#define NG  2    // row-groups per block (32 rows/block)
#define TT  2    // feature sub-tiles per wave (8 waves x 32 features = 256)
#define SXW 36   // x row stride (ushorts)
#define SH 264   // h row stride
#define SM 66    // msg row stride

__global__ __launch_bounds__(512, 4) void md5_main(
    const float* __restrict__ msg,   // (16384,64)
    const float* __restrict__ st0,   // (16384,16)
    const float* __restrict__ b1,    // (64,256)
    const float* __restrict__ b2,    // (64,256)
    const float* __restrict__ b3,    // (64,16)
    const unsigned short* __restrict__ P,
    float* __restrict__ out)         // (16384,16)
{
  __shared__ unsigned short xh[NG][16][SXW], xl[NG][16][SXW];
  __shared__ unsigned short hA[NG][16][SH], hB[NG][16][SH];
  __shared__ unsigned short msgb[NG*16][SM], msgl[NG*16][SM];

  const int tid  = threadIdx.x;
  const int wv   = tid >> 6;        // 0..7
  const int lane = tid & 63;
  const int q    = lane >> 4;
  const int ln   = lane & 15;
  const int row0 = blockIdx.x * (NG*16);
  const int l3w  = (blockIdx.x & 1) << 1;   // L3 waves {l3w, l3w+1}
  const int scw  = l3w ^ 2;                 // scatter wave on the other SIMD pair

  const unsigned short* P1 = P;
  const unsigned short* P2 = P + (size_t)N1G * 8;
  const unsigned short* P3 = P + (size_t)(N1G + N2G) * 8;

  // zero x buffers once (pad cols 22..35 must stay 0 forever)
  for (int i = tid; i < NG*16*SXW; i += 512) {
    (&xh[0][0][0])[i] = 0; (&xl[0][0][0])[i] = 0;
  }
  // msg preload (shared, hi/lo): 32 rows x 64 = 2048 elems / 512 thr = 4 each
  {
    int idx = tid * 4, rr = idx >> 6, cc = idx & 63;
    floatx4 v0 = *(const floatx4*)(msg + (size_t)(row0 + rr)*64 + cc);
    #pragma unroll
    for (int j = 0; j < 4; ++j) {
      BfPair p0 = split2(v0[j]);
      msgb[rr][cc + j] = p0.h;  msgl[rr][cc + j] = p0.l;
    }
  }
  // init state: one wave suffices (ordered by the barrier below)
  if (wv == 0) {
    #pragma unroll
    for (int g = 0; g < NG; ++g) {
      floatx4 v = *(const floatx4*)(st0 + (size_t)(row0 + g*16 + ln)*16 + 4*q);
      ushort4v h4, l4;
      #pragma unroll
      for (int e = 0; e < 4; ++e) { BfPair p = split2(v[e]); h4[e] = p.h; l4[e] = p.l; }
      *(ushort4v*)&xh[g][ln][4*q] = h4;
      *(ushort4v*)&xl[g][ln][4*q] = l4;
    }
  }
  __syncthreads();   // msgb/msgl + state + zero-pads ready
  // round-0 word+rinfo: every wave writes the full (identical) set so its own
  // L1 reads are covered without another barrier (benign identical-value race)
  if (lane < NG*16) {
    int g = lane >> 4, n = lane & 15, rrow = lane;
    int s = c_sched[0];
    BfPair i1p = split2(c_shift[0] / 25.0f);
    #pragma unroll
    for (int j = 0; j < 4; ++j) {
      xh[g][n][16+j] = msgb[rrow][4*s+j];
      xl[g][n][16+j] = msgl[rrow][4*s+j];
    }
    xh[g][n][20] = 0;     xl[g][n][20] = 0;   // round 0: i/64 = 0
    xh[g][n][21] = i1p.h; xl[g][n][21] = i1p.l;
  }

  // ---- prefetched regs for round r: a1/bb1 (L1) + bb2 (L2 acc init) ----
  // Uniform, 20 VGPRs, refreshed after barrier C each round (latency hides
  // under the L3 phase + barrier D instead of sitting on the critical path).
  bf16x8  a1c[TT];  floatx4 bb1c[TT], bb2c[TT];
  {
    const unsigned short* p1 = P1 + ((size_t)(TT*wv)*64 + lane)*8;
    #pragma unroll
    for (int tt = 0; tt < TT; ++tt) {
      a1c[tt]  = *(const bf16x8*)(p1 + (size_t)tt*512);
      bb1c[tt] = *(const floatx4*)(b1 + (TT*wv + tt)*16 + 4*q);
      bb2c[tt] = *(const floatx4*)(b2 + (TT*wv + tt)*16 + 4*q);
    }
  }

  #pragma unroll 1
  for (int r = 0; r < 64; ++r) {
    // -------- Layer 1: x @ W1 -> h1 (own 32-feature slice, both groups) ----
    bf16x8 bxh[NG], bxl[NG];
    #pragma unroll
    for (int g = 0; g < NG; ++g) {
      bxh[g] = *(const bf16x8*)&xh[g][ln][8*q];
      bxl[g] = *(const bf16x8*)&xl[g][ln][8*q];
    }
    #pragma unroll
    for (int tt = 0; tt < TT; ++tt) {
      int f0 = (TT*wv + tt)*16 + 4*q;
      #pragma unroll
      for (int g = 0; g < NG; ++g) {
        floatx4 acc = bb1c[tt];
        acc = mfma16(a1c[tt], bxl[g], acc);
        acc = mfma16(a1c[tt], bxh[g], acc);
        ushort4v h4;
        #pragma unroll
        for (int e = 0; e < 4; ++e) h4[e] = bfbits((__bf16)gelu_f(acc[e]));
        *(ushort4v*)&hA[g][ln][f0] = h4;
      }
    }
    __syncthreads();                       // (B) h1 ready; hB free

    // -------- Layer 2: h1 @ W2 -> h2 (own slice, both groups) --------
    bf16x8 Bf[NG][8];
    #pragma unroll
    for (int g = 0; g < NG; ++g)
      #pragma unroll
      for (int c = 0; c < 8; ++c) Bf[g][c] = *(const bf16x8*)&hA[g][ln][32*c + 8*q];

    const unsigned short* p2 = P2 + ((size_t)((r*16 + TT*wv)*8)*64 + lane)*8;
    #pragma unroll
    for (int tt = 0; tt < TT; ++tt) {
      bf16x8 a2[8];
      #pragma unroll
      for (int c = 0; c < 8; ++c)
        a2[c] = *(const bf16x8*)(p2 + (size_t)(tt*8 + c)*512);
      int f0 = (TT*wv + tt)*16 + 4*q;
      #pragma unroll
      for (int g = 0; g < NG; ++g) {
        floatx4 acc = bb2c[tt];
        #pragma unroll
        for (int c = 0; c < 8; ++c) acc = mfma16(a2[c], Bf[g][c], acc);
        ushort4v h4;
        #pragma unroll
        for (int e = 0; e < 4; ++e) h4[e] = bfbits((__bf16)gelu_f(acc[e]));
        *(ushort4v*)&hB[g][ln][f0] = h4;
      }
    }
    __syncthreads();                       // (C) h2 ready

    // -------- prefetch next round's a1/bb1/bb2 (hides under L3 + barrier D)
    if (r < 63) {
      const unsigned short* p1n = P1 + ((size_t)((r+1)*16 + TT*wv)*64 + lane)*8;
      #pragma unroll
      for (int tt = 0; tt < TT; ++tt) {
        a1c[tt]  = *(const bf16x8*)(p1n + (size_t)tt*512);
        bb1c[tt] = *(const floatx4*)(b1 + (r+1)*256 + (TT*wv + tt)*16 + 4*q);
        bb2c[tt] = *(const floatx4*)(b2 + (r+1)*256 + (TT*wv + tt)*16 + 4*q);
      }
    }

    // -------- Layer 3 (distributed; SIMD-parity-balanced wave pair) --------
    // a3/bb3 loaded inside the branch: contained live range, no spill.
    if (wv == l3w || wv == l3w + 1) {
      const int g = wv - l3w;
      const unsigned short* p3 = P3 + ((size_t)(r*8)*64 + lane)*8;
      bf16x8 a3[8];
      #pragma unroll
      for (int c = 0; c < 8; ++c) a3[c] = *(const bf16x8*)(p3 + (size_t)c*512);
      floatx4 s = *(const floatx4*)(b3 + r*16 + 4*q);
      #pragma unroll
      for (int c = 0; c < 8; ++c) {
        bf16x8 bh = *(const bf16x8*)&hB[g][ln][32*c + 8*q];
        s = mfma16(a3[c], bh, s);
      }
      if (r == 63) {
        *(floatx4*)(out + (size_t)(row0 + g*16 + ln)*16 + 4*q) = s;
      } else {
        ushort4v h4, l4;
        #pragma unroll
        for (int e = 0; e < 4; ++e) { BfPair p = split2(s[e]); h4[e] = p.h; l4[e] = p.l; }
        *(ushort4v*)&xh[g][ln][4*q] = h4;
        *(ushort4v*)&xl[g][ln][4*q] = l4;
      }
    }
    // word + rinfo for next round: scatter wave (other SIMD pair)
    if (wv == scw && lane < NG*16 && r < 63) {
      int g = lane >> 4, n = lane & 15, rrow = lane;
      int sc = c_sched[r+1];
      float i0 = (float)(r+1) * 0.015625f;   // exact in bf16
      BfPair i1p = split2(c_shift[r+1] / 25.0f);
      #pragma unroll
      for (int j = 0; j < 4; ++j) {
        xh[g][n][16+j] = msgb[rrow][4*sc+j];
        xl[g][n][16+j] = msgl[rrow][4*sc+j];
      }
      xh[g][n][20] = bfbits((__bf16)i0); xl[g][n][20] = 0;
      xh[g][n][21] = i1p.h;              xl[g][n][21] = i1p.l;
    }
    if (r < 63) __syncthreads();           // (D) x ready for next L1
  }
}

// ---------------------------------------------------------------------------
extern "C" void kernel_launch(void* const* d_in, const int* in_sizes, int n_in,
                              void* d_out, int out_size, void* d_ws, size_t ws_size,
                              hipStream_t stream) {
  const float* msg = (const float*)d_in[0];
  const float* st0 = (const float*)d_in[1];
  const float* W1  = (const float*)d_in[2];
  const float* b1  = (const float*)d_in[3];
  const float* W2  = (const float*)d_in[4];
  const float* b2  = (const float*)d_in[5];
  const float* W3  = (const float*)d_in[6];
  const float* b3  = (const float*)d_in[7];
  float* out = (float*)d_out;
  (void)in_sizes; (void)n_in; (void)out_size; (void)ws_size;

  unsigned short* P = (unsigned short*)d_ws;
  const int totalGroups = N1G + N2G + N3G;   // 622592
  pack_w<<<(totalGroups + 255) / 256, 256, 0, stream>>>(W1, W2, W3, P);
  md5_main<<<512, 512, 0, stream>>>(msg, st0, b1, b2, b3, P, out);
}